// Round 14
// baseline (755.368 us; speedup 1.0000x reference)
//
#include <hip/hip_runtime.h>

// FGIAN BiLSTM+attention. R18: xp stored TRANSPOSED (xpT[col][row]).
// The gemm epilogue's MFMA fragment (col=lane&15, row=quad*4+rg) made the
// [row][col] layout unvectorizable (64 scalar dword stores/thread). In
// xpT[col][row] each lane's 4 rg-values are CONTIGUOUS -> 16 dwordx4 stores
// (4x fewer store instructions, same bytes/segments). k_scan (sole consumer)
// reads its gate column as xg[p] (stride-1 along t; each 64B line serves 16
// steps). Bit-identical values everywhere -> absmax must stay 9.77e-4.
// k_scan core FROZEN (R11 form, 233us). Everything else = R17.

#define B 128
#define TBODY 512
#define TPUN 256
#define EMB 300
#define EMBP 320
#define VOCAB 50000
#define HID 64
#define G4 256
#define NG 512
#define DM 128

typedef __attribute__((ext_vector_type(8))) short bf16x8;
typedef __attribute__((ext_vector_type(4))) float floatx4;
typedef __attribute__((ext_vector_type(2))) float f32x2;
typedef unsigned short u16;

// ---- workspace layout (bytes) ----
#define OFF_XPB   0u                    // f32 xpT body [NG][B*TBODY] = 134217728
#define OFF_XPP   134217728u            // f32 xpT pun  [NG][B*TPUN]  =  67108864
#define OFF_BODYM 201326592u            // f32 [B*TBODY*DM] =  33554432
#define OFF_PUNM  234881024u            // f32 [B*TPUN*DM]  =  16777216
#define OFF_SMALL 251658240u
// overlays in xpB (dead after k_scan):
#define OFF_ABODY (OFF_XPB + 0u)
#define OFF_APUN  (OFF_XPB + 262144u)
#define OFF_MT    (OFF_XPB + 393216u)
#define OFF_MP    (OFF_XPB + 655360u)
#define OFF_COLP  (OFF_XPB + 786432u)
// overlays in bodyM/punM (dead until k_scan fully overwrites them):
#define OFF_EMBB  OFF_BODYM             // bf16 [VOCAB*EMBP] = 32000000
#define OFF_WCB   OFF_PUNM
#define OFF_WCP   (OFF_PUNM + 327680u)
#define OFF_BIASB (OFF_PUNM + 655360u)
#define OFF_BIASP (OFF_PUNM + 657408u)
#define OFF_LENS  OFF_SMALL
#define OFF_FEAT  (OFF_SMALL + 1024u)

__device__ inline u16 f2bf(float v) {
    unsigned int u = __float_as_uint(v);
    unsigned int r = (u + 0x7FFFu + ((u >> 16) & 1u)) >> 16;  // RNE
    return (u16)r;
}

__device__ inline void gload_lds16(const void* g, void* l) {
    __builtin_amdgcn_global_load_lds(
        (const __attribute__((address_space(1))) unsigned int*)g,
        (__attribute__((address_space(3))) unsigned int*)l, 16, 0, 0);
}

// quad_perm broadcast of quad-lane gg (0..3): ctrl = gg*0x55 (HW-ok, R9-R11)
#define QBC(v, gg) __int_as_float(__builtin_amdgcn_update_dpp( \
    0, __float_as_int(v), (gg) * 0x55, 0xF, 0xF, true))
// packed dual f32 FMA (HW-ok, R6/R17)
#define PKFMA2(acc, a2, b2) \
    asm("v_pk_fma_f32 %0, %1, %2, %0" : "+v"(acc) : "v"(a2), "v"(b2));

// ---------------- fused prep: emb->bf16 | lens | weights concat ----------------
// blocks [0,15625): emb (4 elems/thread); [15625,15881): lens; rest: prep_w.
__global__ __launch_bounds__(256) void k_prep(
    const float* __restrict__ emb, u16* __restrict__ embb,
    const int* __restrict__ bidx, const int* __restrict__ pidx,
    int* __restrict__ lens,
    const float* __restrict__ bWih_f, const float* __restrict__ bWih_b,
    const float* __restrict__ bb_f, const float* __restrict__ bb_b,
    const float* __restrict__ pWih_f, const float* __restrict__ pWih_b,
    const float* __restrict__ pb_f, const float* __restrict__ pb_b,
    u16* __restrict__ Wcb, u16* __restrict__ Wcp,
    float* __restrict__ biasb, float* __restrict__ biasp) {
    int blk = blockIdx.x, tid = threadIdx.x;
    if (blk < 15625) {
        int e4 = (blk * 256 + tid) * 4;  // exactly VOCAB*EMBP/4 threads
        int row = e4 / EMBP, d = e4 - row * EMBP;
        u16 o0 = 0, o1 = 0, o2 = 0, o3 = 0;
        if (d < EMB) {
            float4 v = *(const float4*)(emb + (size_t)row * EMB + d);
            o0 = f2bf(v.x); o1 = f2bf(v.y); o2 = f2bf(v.z); o3 = f2bf(v.w);
        }
        ushort4 o = {o0, o1, o2, o3};
        *(ushort4*)(embb + e4) = o;
    } else if (blk < 15625 + 256) {
        int j = blk - 15625;
        const int* src; int n;
        if (j < B) { src = bidx + (size_t)j * TBODY; n = TBODY; }
        else       { src = pidx + (size_t)(j - B) * TPUN; n = TPUN; }
        int c = 0;
        for (int t = tid; t < n; t += 256) c += (src[t] != 0) ? 1 : 0;
        for (int o = 32; o; o >>= 1) c += __shfl_xor(c, o, 64);
        __shared__ int red[4];
        if ((tid & 63) == 0) red[tid >> 6] = c;
        __syncthreads();
        if (tid == 0) lens[j] = red[0] + red[1] + red[2] + red[3];
    } else {
        int e = (blk - 15881) * 256 + tid;   // 1284 blocks cover 328704 exactly
        const int WSZ = NG * EMBP;  // 163840
        if (e < WSZ) {
            int g = e / EMBP, d = e - g * EMBP;
            float v = 0.f;
            if (d < EMB) v = (g < G4) ? bWih_f[g * EMB + d] : bWih_b[(g - G4) * EMB + d];
            Wcb[e] = f2bf(v);
        } else if (e < 2 * WSZ) {
            int ee = e - WSZ;
            int g = ee / EMBP, d = ee - g * EMBP;
            float v = 0.f;
            if (d < EMB) v = (g < G4) ? pWih_f[g * EMB + d] : pWih_b[(g - G4) * EMB + d];
            Wcp[ee] = f2bf(v);
        } else if (e < 2 * WSZ + NG) {
            int g = e - 2 * WSZ;
            biasb[g] = (g < G4) ? bb_f[g] : bb_b[g - G4];
        } else if (e < 2 * WSZ + 2 * NG) {
            int g = e - 2 * WSZ - NG;
            biasp[g] = (g < G4) ? pb_f[g] : pb_b[g - G4];
        }
    }
}

// ---------------- 128x128 bf16 MFMA GEMM -> TRANSPOSED output --------------
// outT[col][row], leading dim mtot. Lane's 4 rg-values (rows r0..r0+3, one
// column) are contiguous -> one dwordx4 store per (a,c).
__global__ __launch_bounds__(256) void k_gemm(const int* __restrict__ idx,
                                              const u16* __restrict__ embb,
                                              const u16* __restrict__ Wc,
                                              const float* __restrict__ biasc,
                                              float* __restrict__ outT,
                                              int mtot) {
    __shared__ u16 As[128 * 32];
    __shared__ u16 Bs[128 * 32];
    int tid = threadIdx.x, wave = tid >> 6, lane = tid & 63;
    int m0 = blockIdx.x * 128, g0 = blockIdx.y * 128;

    const u16* agp[2]; const u16* bgp[2];
    u16* asd[2]; u16* bsd[2];
#pragma unroll
    for (int j = 0; j < 2; j++) {
        int rbase = wave * 32 + j * 16;
        int r = rbase + (lane >> 2);
        int clog = (lane & 3) ^ (r & 3);
        int arow = idx[m0 + r];
        agp[j] = embb + (size_t)arow * EMBP + clog * 8;
        bgp[j] = Wc + (size_t)(g0 + r) * EMBP + clog * 8;
        asd[j] = As + rbase * 32;
        bsd[j] = Bs + rbase * 32;
    }

    int l15 = lane & 15, quad = lane >> 4;
    int mt0 = (wave >> 1) * 4, nt0 = (wave & 1) * 4;
    const u16* ard[4]; const u16* brd[4];
#pragma unroll
    for (int a = 0; a < 4; a++) {
        int r = (mt0 + a) * 16 + l15;
        ard[a] = As + r * 32 + ((quad ^ (r & 3)) * 8);
        int n = (nt0 + a) * 16 + l15;
        brd[a] = Bs + n * 32 + ((quad ^ (n & 3)) * 8);
    }

    floatx4 acc[4][4];
#pragma unroll
    for (int a = 0; a < 4; a++)
#pragma unroll
        for (int c = 0; c < 4; c++) acc[a][c] = (floatx4){0.f, 0.f, 0.f, 0.f};

    for (int k0 = 0; k0 < EMBP; k0 += 32) {
#pragma unroll
        for (int j = 0; j < 2; j++) {
            gload_lds16(agp[j] + k0, asd[j]);
            gload_lds16(bgp[j] + k0, bsd[j]);
        }
        __syncthreads();
        bf16x8 af[4], bfr[4];
#pragma unroll
        for (int a = 0; a < 4; a++) { af[a] = *(const bf16x8*)ard[a]; bfr[a] = *(const bf16x8*)brd[a]; }
#pragma unroll
        for (int a = 0; a < 4; a++)
#pragma unroll
            for (int c = 0; c < 4; c++)
                acc[a][c] = __builtin_amdgcn_mfma_f32_16x16x32_bf16(af[a], bfr[c], acc[a][c], 0, 0, 0);
        __syncthreads();
    }

#pragma unroll
    for (int c = 0; c < 4; c++) {
        int gcol = g0 + (nt0 + c) * 16 + l15;
        float bv = biasc[gcol];
        float* cb = outT + (size_t)gcol * mtot + m0;
#pragma unroll
        for (int a = 0; a < 4; a++) {
            int r0 = (mt0 + a) * 16 + quad * 4;
            float4 v = {acc[a][c][0] + bv, acc[a][c][1] + bv,
                        acc[a][c][2] + bv, acc[a][c][3] + bv};
            *(float4*)(cb + r0) = v;
        }
    }
}

// ---------------- LSTM scans: 1 block (4 waves) per (seq,dir,b) ----------------
// wave w owns units 16w..16w+15; lane l: gate g=l&3, unit u=w*16+(l>>2).
// Replica ds_read_b128 gives lane l h-quad (l&15). Matvec: 16 groups, group n
// uses v_fmac_f32_dpp row_ror:n against PER-LANE PRE-ROTATED weight group n.
// Barrier = raw lgkmcnt(0)+s_barrier. x prefetched 2 steps deep. R18: x read
// from TRANSPOSED xpT -> xg[p] stride-1 (each 64B line serves 16 steps).
#define DECLWR(n) \
    float Wr##n##0, Wr##n##1, Wr##n##2, Wr##n##3; \
    { int qs_ = (((l16 - (n)) & 15) << 2); \
      Wr##n##0 = vw[qs_]; Wr##n##1 = vw[qs_ + 1]; \
      Wr##n##2 = vw[qs_ + 2]; Wr##n##3 = vw[qs_ + 3]; }
#define FMACD(ACC, H, W, N) \
    asm("v_fmac_f32_dpp %0, %1, %2 row_ror:" #N " row_mask:0xf bank_mask:0xf" \
        : "+v"(ACC) : "v"(H), "v"(W));
#define RORF(n) { \
    FMACD(a0, hq.x, Wr##n##0, n) FMACD(a1, hq.y, Wr##n##1, n) \
    FMACD(a2, hq.z, Wr##n##2, n) FMACD(a3, hq.w, Wr##n##3, n) }

// one LSTM step; XR is used for this step then refilled with step S+2's x
#define SBODY(S, XR) { \
    int p_ = dir ? (len - 1 - (S)) : (S); \
    float xv = XR; \
    int pn_ = dir ? (len - 3 - (S)) : ((S) + 2); \
    pn_ = min(max(pn_, 0), T - 1); \
    XR = xg[pn_]; \
    float4 hq = *(const float4*)(&hbuf[(S) & 1][l16 * 4]); \
    float a0 = xv, a1 = 0.f, a2 = 0.f, a3 = 0.f; \
    a0 = fmaf(hq.x, Wr00, a0); a1 = fmaf(hq.y, Wr01, a1); \
    a2 = fmaf(hq.z, Wr02, a2); a3 = fmaf(hq.w, Wr03, a3); \
    RORF(1)  RORF(2)  RORF(3)  RORF(4)  RORF(5) \
    RORF(6)  RORF(7)  RORF(8)  RORF(9)  RORF(10) \
    RORF(11) RORF(12) RORF(13) RORF(14) RORF(15) \
    float pre = (a0 + a1) + (a2 + a3); \
    bool isg = (g == 2); \
    float t_in = isg ? (2.f * pre) : (-pre); \
    float e_ = __expf(t_in); \
    float r_ = __builtin_amdgcn_rcpf(1.f + e_); \
    float val = isg ? fmaf(-2.f, r_, 1.f) : r_; \
    float vi = QBC(val, 0); \
    float vf = QBC(val, 1); \
    float vg = QBC(val, 2); \
    float vo = QBC(val, 3); \
    c = fmaf(vf, c, vi * vg); \
    float th = fmaf(-2.f, __builtin_amdgcn_rcpf(1.f + __expf(2.f * c)), 1.f); \
    float h = vo * th; \
    if (g == 0) { \
        hbuf[((S) & 1) ^ 1][u] = h; \
        outp[(size_t)p_ * DM + u] = h; \
    } \
    asm volatile("s_waitcnt lgkmcnt(0)\n\ts_barrier" ::: "memory"); }

__global__ __attribute__((amdgpu_flat_work_group_size(256, 256),
                          amdgpu_waves_per_eu(2, 2))) void k_scan(
    const float* __restrict__ xpB, const float* __restrict__ xpP,
    float* __restrict__ bodyM, float* __restrict__ punM,
    const int* __restrict__ lens,
    const float* __restrict__ bWhh_f, const float* __restrict__ bWhh_b,
    const float* __restrict__ pWhh_f, const float* __restrict__ pWhh_b) {
    int task = blockIdx.x, tid = threadIdx.x;
    int isPun = task >> 8;
    int sub = task & 255;
    int b = sub & 127, dir = sub >> 7;
    int T = isPun ? TPUN : TBODY;
    int MT = isPun ? (B * TPUN) : (B * TBODY);
    int len = lens[(isPun ? B : 0) + b];
    int w = tid >> 6, l = tid & 63;
    int g = l & 3, q = l >> 2;
    int u = w * 16 + q;
    int l16 = l & 15;
    const float* xpS = isPun ? xpP : xpB;
    float* outp = (isPun ? punM : bodyM) + (size_t)b * T * DM + dir * HID;
    const float* Whh = isPun ? (dir ? pWhh_b : pWhh_f) : (dir ? bWhh_b : bWhh_f);

    // 64 weights (this lane's gate row) as named scalars, PRE-ROTATED so
    // group n matches row_ror:n of the replica hq. Volatile = load once.
    const volatile float* vw = Whh + (size_t)(g * 64 + u) * 64;
    DECLWR(0)  DECLWR(1)  DECLWR(2)  DECLWR(3)
    DECLWR(4)  DECLWR(5)  DECLWR(6)  DECLWR(7)
    DECLWR(8)  DECLWR(9)  DECLWR(10) DECLWR(11)
    DECLWR(12) DECLWR(13) DECLWR(14) DECLWR(15)

    __shared__ __align__(16) float hbuf[2][64];
    if (tid < 64) hbuf[0][tid] = 0.f;
    __syncthreads();

    if (len > 0) {
        // this lane's gate preact column, TRANSPOSED layout: stride-1 in t
        const float* xg = xpS + (size_t)(dir * G4 + g * 64 + u) * MT + (size_t)b * T;
        float c = 0.f;
        // 2-deep x prefetch: xA for even steps, xB for odd steps
        int p0 = dir ? (len - 1) : 0;
        int p1 = dir ? (len - 2) : 1;
        p1 = min(max(p1, 0), T - 1);
        float xA = xg[p0];
        float xB = xg[p1];
        int s = 0;
        for (; s + 1 < len; s += 2) {
            SBODY(s, xA)
            SBODY(s + 1, xB)
        }
        if (s < len) { SBODY(s, xA) }
    }
    // tail zeroing: rows [len,T) must be 0 (replaces the global memset).
    if (g == 0) {
        for (int p = max(len, 0); p < T; ++p)
            outp[(size_t)p * DM + u] = 0.f;
    }
}

// ---------------- a_t = body_M.w1, b_p = pun_M.w2 (one wave per row) ----------------
__global__ __launch_bounds__(256) void k_rowdot(const float* __restrict__ bodyM,
                                                const float* __restrict__ punM,
                                                const float* __restrict__ w_u,
                                                float* __restrict__ a_body,
                                                float* __restrict__ a_pun) {
    int wid = (blockIdx.x * 256 + threadIdx.x) >> 6;
    int lane = threadIdx.x & 63;
    const int NB = B * TBODY;
    const float* src; const float* wv; float* dst;
    if (wid < NB) { src = bodyM + (size_t)wid * DM; wv = w_u; dst = a_body + wid; }
    else { src = punM + (size_t)(wid - NB) * DM; wv = w_u + DM; dst = a_pun + (wid - NB); }
    float2 v = ((const float2*)src)[lane];
    float2 w = ((const float2*)wv)[lane];
    float s = v.x * w.x + v.y * w.y;
    for (int o = 32; o; o >>= 1) s += __shfl_xor(s, o, 64);
    if (lane == 0) *dst = s;
}

// ---------------- align tile: m_t (full) + col partial maxes ----------------
__global__ __launch_bounds__(256) void k_align(
    const float* __restrict__ bodyM, const float* __restrict__ punM,
    const float* __restrict__ a_body, const float* __restrict__ a_pun,
    const float* __restrict__ w_u,
    float* __restrict__ m_t, float* __restrict__ colpart) {
    __shared__ float bw[64 * 132];
    __shared__ float pu[64 * 132];
    __shared__ float colred[64 * 16];
    int tid = threadIdx.x;
    int tt = blockIdx.x, b = blockIdx.y;
    int t0 = tt * 64;
    int ti = tid >> 4, pi = tid & 15;
    const float* w3 = w_u + 2 * DM;
    const float* bsrc = bodyM + ((size_t)b * TBODY + t0) * DM;
#pragma unroll
    for (int j = 0; j < 8; j++) {
        int e = tid + 256 * j;
        int i = e >> 5, c4 = e & 31;
        float4 v = *(const float4*)(bsrc + i * DM + c4 * 4);
        float4 wv = *(const float4*)(w3 + c4 * 4);
        v.x *= wv.x; v.y *= wv.y; v.z *= wv.z; v.w *= wv.w;
        *(float4*)(bw + i * 132 + c4 * 4) = v;
    }
    float aB[4];
#pragma unroll
    for (int a = 0; a < 4; a++) aB[a] = a_body[(size_t)b * TBODY + t0 + ti * 4 + a];
    float mrun[4] = {-1e30f, -1e30f, -1e30f, -1e30f};
    for (int pc = 0; pc < 4; pc++) {
        __syncthreads();
        const float* psrc = punM + ((size_t)b * TPUN + pc * 64) * DM;
#pragma unroll
        for (int j = 0; j < 8; j++) {
            int e = tid + 256 * j;
            int i = e >> 5, c4 = e & 31;
            float4 v = *(const float4*)(psrc + i * DM + c4 * 4);
            *(float4*)(pu + i * 132 + c4 * 4) = v;
        }
        __syncthreads();
        float aP[4];
#pragma unroll
        for (int c = 0; c < 4; c++) aP[c] = a_pun[(size_t)b * TPUN + pc * 64 + pi * 4 + c];
        f32x2 C2[4][4];
#pragma unroll
        for (int a = 0; a < 4; a++)
#pragma unroll
            for (int c = 0; c < 4; c++) C2[a][c] = (f32x2){0.f, 0.f};
        for (int d4 = 0; d4 < 32; d4++) {
            float4 bq[4];
#pragma unroll
            for (int a = 0; a < 4; a++) bq[a] = *(const float4*)(bw + (ti * 4 + a) * 132 + d4 * 4);
            float4 pq[4];
#pragma unroll
            for (int c = 0; c < 4; c++) pq[c] = *(const float4*)(pu + (pi * 4 + c) * 132 + d4 * 4);
#pragma unroll
            for (int a = 0; a < 4; a++) {
                f32x2 blo = {bq[a].x, bq[a].y};
                f32x2 bhi = {bq[a].z, bq[a].w};
#pragma unroll
                for (int c = 0; c < 4; c++) {
                    f32x2 plo = {pq[c].x, pq[c].y};
                    f32x2 phi = {pq[c].z, pq[c].w};
                    PKFMA2(C2[a][c], blo, plo)
                    PKFMA2(C2[a][c], bhi, phi)
                }
            }
        }
        float colv[4] = {-1e30f, -1e30f, -1e30f, -1e30f};
#pragma unroll
        for (int a = 0; a < 4; a++) {
            float rm = -1e30f;
#pragma unroll
            for (int c = 0; c < 4; c++) {
                float valv = (C2[a][c].x + C2[a][c].y) + aB[a] + aP[c];
                rm = fmaxf(rm, valv);
                colv[c] = fmaxf(colv[c], valv);
            }
#pragma unroll
            for (int o = 1; o < 16; o <<= 1) rm = fmaxf(rm, __shfl_xor(rm, o, 64));
            mrun[a] = fmaxf(mrun[a], rm);
        }
#pragma unroll
        for (int c = 0; c < 4; c++) colred[(pi * 4 + c) * 16 + ti] = colv[c];
        __syncthreads();
        if (tid < 64) {
            float m = -1e30f;
#pragma unroll
            for (int k = 0; k < 16; k++) m = fmaxf(m, colred[tid * 16 + k]);
            colpart[((size_t)b * 8 + tt) * TPUN + pc * 64 + tid] = m;
        }
    }
    if (pi == 0) {
#pragma unroll
        for (int a = 0; a < 4; a++) m_t[(size_t)b * TBODY + t0 + ti * 4 + a] = mrun[a];
    }
}

__global__ __launch_bounds__(256) void k_colmax(const float* __restrict__ colpart,
                                                float* __restrict__ m_p) {
    int b = blockIdx.x, p = threadIdx.x;
    float m = -1e30f;
    for (int tt = 0; tt < 8; tt++) m = fmaxf(m, colpart[((size_t)b * 8 + tt) * TPUN + p]);
    m_p[(size_t)b * TPUN + p] = m;
}

// ---------------- softmax + attention-weighted feature sums ----------------
__global__ __launch_bounds__(256) void k_feat(const float* __restrict__ bodyM,
                                              const float* __restrict__ punM,
                                              const float* __restrict__ m_t,
                                              const float* __restrict__ m_p,
                                              float* __restrict__ feat) {
    int bidx = blockIdx.x;
    int b = bidx & (B - 1), which = bidx >> 7;
    int n = which ? TPUN : TBODY;
    const float* sc = which ? (m_p + (size_t)b * TPUN) : (m_t + (size_t)b * TBODY);
    const float* src = which ? (punM + (size_t)b * TPUN * DM) : (bodyM + (size_t)b * TBODY * DM);
    float* dst = feat + (size_t)b * 256 + which * DM;
    int tid = threadIdx.x;
    __shared__ float e_lds[TBODY];
    __shared__ float red[8];
    __shared__ float red2[256];
    float mx = -1e30f;
    for (int t = tid; t < n; t += 256) mx = fmaxf(mx, sc[t]);
    for (int o = 32; o; o >>= 1) mx = fmaxf(mx, __shfl_xor(mx, o, 64));
    if ((tid & 63) == 0) red[tid >> 6] = mx;
    __syncthreads();
    mx = fmaxf(fmaxf(red[0], red[1]), fmaxf(red[2], red[3]));
    float se = 0.f;
    for (int t = tid; t < n; t += 256) {
        float ev = __expf(sc[t] - mx);
        e_lds[t] = ev;
        se += ev;
    }
    for (int o = 32; o; o >>= 1) se += __shfl_xor(se, o, 64);
    if ((tid & 63) == 0) red[4 + (tid >> 6)] = se;
    __syncthreads();
    se = red[4] + red[5] + red[6] + red[7];
    float inv = 1.f / se;
    int d = tid & 127, half = tid >> 7;
    float acc = 0.f;
    for (int t = half; t < n; t += 2) acc += e_lds[t] * src[(size_t)t * DM + d];
    red2[tid] = acc;
    __syncthreads();
    if (tid < DM) dst[tid] = (red2[tid] + red2[tid + 128]) * inv;
}

// ---------------- out = feat @ Wd^T + bd ----------------
__global__ __launch_bounds__(256) void k_out(const float* __restrict__ feat,
                                             const float* __restrict__ Wd,
                                             const float* __restrict__ bd,
                                             float* __restrict__ outp) {
    int b = blockIdx.x, tid = threadIdx.x;
    float v = feat[(size_t)b * 256 + tid];
    __shared__ float red[12];
#pragma unroll
    for (int pol = 0; pol < 3; pol++) {
        float s = v * Wd[pol * 256 + tid];
        for (int o = 32; o; o >>= 1) s += __shfl_xor(s, o, 64);
        if ((tid & 63) == 0) red[pol * 4 + (tid >> 6)] = s;
    }
    __syncthreads();
    if (tid < 3) outp[b * 3 + tid] = red[tid * 4] + red[tid * 4 + 1] + red[tid * 4 + 2] + red[tid * 4 + 3] + bd[tid];
}

extern "C" void kernel_launch(void* const* d_in, const int* in_sizes, int n_in,
                              void* d_out, int out_size, void* d_ws, size_t ws_size,
                              hipStream_t stream) {
    const int* body_idx = (const int*)d_in[0];
    const int* pun_idx  = (const int*)d_in[1];
    const float* emb    = (const float*)d_in[2];
    const float* w_u    = (const float*)d_in[3];
    const float* Wd     = (const float*)d_in[4];
    const float* bd     = (const float*)d_in[5];
    const float* bWih_f = (const float*)d_in[6];
    const float* bWhh_f = (const float*)d_in[7];
    const float* bb_f   = (const float*)d_in[8];
    const float* bWih_b = (const float*)d_in[9];
    const float* bWhh_b = (const float*)d_in[10];
    const float* bb_b   = (const float*)d_in[11];
    const float* pWih_f = (const float*)d_in[12];
    const float* pWhh_f = (const float*)d_in[13];
    const float* pb_f   = (const float*)d_in[14];
    const float* pWih_b = (const float*)d_in[15];
    const float* pWhh_b = (const float*)d_in[16];
    const float* pb_b   = (const float*)d_in[17];

    char* ws = (char*)d_ws;
    float* xpB   = (float*)(ws + OFF_XPB);
    float* xpP   = (float*)(ws + OFF_XPP);
    float* bodyM = (float*)(ws + OFF_BODYM);
    float* punM  = (float*)(ws + OFF_PUNM);
    u16* embb    = (u16*)(ws + OFF_EMBB);
    u16* Wcb     = (u16*)(ws + OFF_WCB);
    u16* Wcp     = (u16*)(ws + OFF_WCP);
    float* biasb = (float*)(ws + OFF_BIASB);
    float* biasp = (float*)(ws + OFF_BIASP);
    int* lens    = (int*)(ws + OFF_LENS);
    float* a_body = (float*)(ws + OFF_ABODY);
    float* a_pun  = (float*)(ws + OFF_APUN);
    float* m_t    = (float*)(ws + OFF_MT);
    float* m_p    = (float*)(ws + OFF_MP);
    float* colpart = (float*)(ws + OFF_COLP);
    float* feat   = (float*)(ws + OFF_FEAT);
    float* outp   = (float*)d_out;

    k_prep<<<dim3(17165), dim3(256), 0, stream>>>(
        emb, embb, body_idx, pun_idx, lens,
        bWih_f, bWih_b, bb_f, bb_b, pWih_f, pWih_b, pb_f, pb_b,
        Wcb, Wcp, biasb, biasp);
    k_gemm<<<dim3(512, 4), dim3(256), 0, stream>>>(body_idx, embb, Wcb, biasb, xpB, B * TBODY);
    k_gemm<<<dim3(256, 4), dim3(256), 0, stream>>>(pun_idx, embb, Wcp, biasp, xpP, B * TPUN);
    k_scan<<<dim3(512), dim3(256), 0, stream>>>(xpB, xpP, bodyM, punM, lens,
                                                bWhh_f, bWhh_b, pWhh_f, pWhh_b);
    k_rowdot<<<dim3(24576), dim3(256), 0, stream>>>(bodyM, punM, w_u, a_body, a_pun);
    k_align<<<dim3(8, 128), dim3(256), 0, stream>>>(bodyM, punM, a_body, a_pun, w_u, m_t, colpart);
    k_colmax<<<dim3(128), dim3(256), 0, stream>>>(colpart, m_p);
    k_feat<<<dim3(256), dim3(256), 0, stream>>>(bodyM, punM, m_t, m_p, feat);
    k_out<<<dim3(128), dim3(256), 0, stream>>>(feat, Wd, bd, outp);
}

// Round 15
// 593.519 us; speedup vs baseline: 1.2727x; 1.2727x over previous
//
#include <hip/hip_runtime.h>

// FGIAN BiLSTM+attention. R19 = exact revert to R17 (best: 592us).
// R18 post-mortem: xpT[col][row] destroyed WAVE coalescing in k_scan — 256
// lanes' addresses 256KB apart -> one 64B line per lane per step, lines
// evicted before the 16-step reuse window -> FETCH 99MB->760MB (7.6x),
// k_scan 233->393us. Layout must serve the BW-critical reader's coalescing.
// k_scan FROZEN (R11 form); k_align pk_fma (R17); fused k_prep (R17);
// no memset (R17 tail-zeroing).

#define B 128
#define TBODY 512
#define TPUN 256
#define EMB 300
#define EMBP 320
#define VOCAB 50000
#define HID 64
#define G4 256
#define NG 512
#define DM 128

typedef __attribute__((ext_vector_type(8))) short bf16x8;
typedef __attribute__((ext_vector_type(4))) float floatx4;
typedef __attribute__((ext_vector_type(2))) float f32x2;
typedef unsigned short u16;

// ---- workspace layout (bytes) ----
#define OFF_XPB   0u                    // f32 [B*TBODY*NG] = 134217728
#define OFF_XPP   134217728u            // f32 [B*TPUN*NG]  =  67108864
#define OFF_BODYM 201326592u            // f32 [B*TBODY*DM] =  33554432
#define OFF_PUNM  234881024u            // f32 [B*TPUN*DM]  =  16777216
#define OFF_SMALL 251658240u
// overlays in xpB (dead after k_scan):
#define OFF_ABODY (OFF_XPB + 0u)
#define OFF_APUN  (OFF_XPB + 262144u)
#define OFF_MT    (OFF_XPB + 393216u)
#define OFF_MP    (OFF_XPB + 655360u)
#define OFF_COLP  (OFF_XPB + 786432u)
// overlays in bodyM/punM (dead until k_scan fully overwrites them):
#define OFF_EMBB  OFF_BODYM             // bf16 [VOCAB*EMBP] = 32000000
#define OFF_WCB   OFF_PUNM
#define OFF_WCP   (OFF_PUNM + 327680u)
#define OFF_BIASB (OFF_PUNM + 655360u)
#define OFF_BIASP (OFF_PUNM + 657408u)
#define OFF_LENS  OFF_SMALL
#define OFF_FEAT  (OFF_SMALL + 1024u)

__device__ inline u16 f2bf(float v) {
    unsigned int u = __float_as_uint(v);
    unsigned int r = (u + 0x7FFFu + ((u >> 16) & 1u)) >> 16;  // RNE
    return (u16)r;
}

__device__ inline void gload_lds16(const void* g, void* l) {
    __builtin_amdgcn_global_load_lds(
        (const __attribute__((address_space(1))) unsigned int*)g,
        (__attribute__((address_space(3))) unsigned int*)l, 16, 0, 0);
}

// quad_perm broadcast of quad-lane gg (0..3): ctrl = gg*0x55 (HW-ok, R9-R11)
#define QBC(v, gg) __int_as_float(__builtin_amdgcn_update_dpp( \
    0, __float_as_int(v), (gg) * 0x55, 0xF, 0xF, true))
// packed dual f32 FMA (HW-ok, R6/R17)
#define PKFMA2(acc, a2, b2) \
    asm("v_pk_fma_f32 %0, %1, %2, %0" : "+v"(acc) : "v"(a2), "v"(b2));

// ---------------- fused prep: emb->bf16 | lens | weights concat ----------------
// blocks [0,15625): emb (4 elems/thread); [15625,15881): lens; rest: prep_w.
__global__ __launch_bounds__(256) void k_prep(
    const float* __restrict__ emb, u16* __restrict__ embb,
    const int* __restrict__ bidx, const int* __restrict__ pidx,
    int* __restrict__ lens,
    const float* __restrict__ bWih_f, const float* __restrict__ bWih_b,
    const float* __restrict__ bb_f, const float* __restrict__ bb_b,
    const float* __restrict__ pWih_f, const float* __restrict__ pWih_b,
    const float* __restrict__ pb_f, const float* __restrict__ pb_b,
    u16* __restrict__ Wcb, u16* __restrict__ Wcp,
    float* __restrict__ biasb, float* __restrict__ biasp) {
    int blk = blockIdx.x, tid = threadIdx.x;
    if (blk < 15625) {
        int e4 = (blk * 256 + tid) * 4;  // exactly VOCAB*EMBP/4 threads
        int row = e4 / EMBP, d = e4 - row * EMBP;
        u16 o0 = 0, o1 = 0, o2 = 0, o3 = 0;
        if (d < EMB) {
            float4 v = *(const float4*)(emb + (size_t)row * EMB + d);
            o0 = f2bf(v.x); o1 = f2bf(v.y); o2 = f2bf(v.z); o3 = f2bf(v.w);
        }
        ushort4 o = {o0, o1, o2, o3};
        *(ushort4*)(embb + e4) = o;
    } else if (blk < 15625 + 256) {
        int j = blk - 15625;
        const int* src; int n;
        if (j < B) { src = bidx + (size_t)j * TBODY; n = TBODY; }
        else       { src = pidx + (size_t)(j - B) * TPUN; n = TPUN; }
        int c = 0;
        for (int t = tid; t < n; t += 256) c += (src[t] != 0) ? 1 : 0;
        for (int o = 32; o; o >>= 1) c += __shfl_xor(c, o, 64);
        __shared__ int red[4];
        if ((tid & 63) == 0) red[tid >> 6] = c;
        __syncthreads();
        if (tid == 0) lens[j] = red[0] + red[1] + red[2] + red[3];
    } else {
        int e = (blk - 15881) * 256 + tid;   // 1284 blocks cover 328704 exactly
        const int WSZ = NG * EMBP;  // 163840
        if (e < WSZ) {
            int g = e / EMBP, d = e - g * EMBP;
            float v = 0.f;
            if (d < EMB) v = (g < G4) ? bWih_f[g * EMB + d] : bWih_b[(g - G4) * EMB + d];
            Wcb[e] = f2bf(v);
        } else if (e < 2 * WSZ) {
            int ee = e - WSZ;
            int g = ee / EMBP, d = ee - g * EMBP;
            float v = 0.f;
            if (d < EMB) v = (g < G4) ? pWih_f[g * EMB + d] : pWih_b[(g - G4) * EMB + d];
            Wcp[ee] = f2bf(v);
        } else if (e < 2 * WSZ + NG) {
            int g = e - 2 * WSZ;
            biasb[g] = (g < G4) ? bb_f[g] : bb_b[g - G4];
        } else if (e < 2 * WSZ + 2 * NG) {
            int g = e - 2 * WSZ - NG;
            biasp[g] = (g < G4) ? pb_f[g] : pb_b[g - G4];
        }
    }
}

// ---------------- 128x128 bf16 MFMA GEMM, global_load_lds staging ----------------
__global__ __launch_bounds__(256) void k_gemm(const int* __restrict__ idx,
                                              const u16* __restrict__ embb,
                                              const u16* __restrict__ Wc,
                                              const float* __restrict__ biasc,
                                              float* __restrict__ out) {
    __shared__ u16 As[128 * 32];
    __shared__ u16 Bs[128 * 32];
    int tid = threadIdx.x, wave = tid >> 6, lane = tid & 63;
    int m0 = blockIdx.x * 128, g0 = blockIdx.y * 128;

    const u16* agp[2]; const u16* bgp[2];
    u16* asd[2]; u16* bsd[2];
#pragma unroll
    for (int j = 0; j < 2; j++) {
        int rbase = wave * 32 + j * 16;
        int r = rbase + (lane >> 2);
        int clog = (lane & 3) ^ (r & 3);
        int arow = idx[m0 + r];
        agp[j] = embb + (size_t)arow * EMBP + clog * 8;
        bgp[j] = Wc + (size_t)(g0 + r) * EMBP + clog * 8;
        asd[j] = As + rbase * 32;
        bsd[j] = Bs + rbase * 32;
    }

    int l15 = lane & 15, quad = lane >> 4;
    int mt0 = (wave >> 1) * 4, nt0 = (wave & 1) * 4;
    const u16* ard[4]; const u16* brd[4];
#pragma unroll
    for (int a = 0; a < 4; a++) {
        int r = (mt0 + a) * 16 + l15;
        ard[a] = As + r * 32 + ((quad ^ (r & 3)) * 8);
        int n = (nt0 + a) * 16 + l15;
        brd[a] = Bs + n * 32 + ((quad ^ (n & 3)) * 8);
    }

    floatx4 acc[4][4];
#pragma unroll
    for (int a = 0; a < 4; a++)
#pragma unroll
        for (int c = 0; c < 4; c++) acc[a][c] = (floatx4){0.f, 0.f, 0.f, 0.f};

    for (int k0 = 0; k0 < EMBP; k0 += 32) {
#pragma unroll
        for (int j = 0; j < 2; j++) {
            gload_lds16(agp[j] + k0, asd[j]);
            gload_lds16(bgp[j] + k0, bsd[j]);
        }
        __syncthreads();
        bf16x8 af[4], bfr[4];
#pragma unroll
        for (int a = 0; a < 4; a++) { af[a] = *(const bf16x8*)ard[a]; bfr[a] = *(const bf16x8*)brd[a]; }
#pragma unroll
        for (int a = 0; a < 4; a++)
#pragma unroll
            for (int c = 0; c < 4; c++)
                acc[a][c] = __builtin_amdgcn_mfma_f32_16x16x32_bf16(af[a], bfr[c], acc[a][c], 0, 0, 0);
        __syncthreads();
    }

#pragma unroll
    for (int c = 0; c < 4; c++) {
        int gcol = g0 + (nt0 + c) * 16 + l15;
        float bv = biasc[gcol];
#pragma unroll
        for (int a = 0; a < 4; a++) {
            int row0 = m0 + (mt0 + a) * 16 + quad * 4;
#pragma unroll
            for (int rg = 0; rg < 4; rg++)
                out[(size_t)(row0 + rg) * NG + gcol] = acc[a][c][rg] + bv;
        }
    }
}

// ---------------- LSTM scans: 1 block (4 waves) per (seq,dir,b) ----------------
// wave w owns units 16w..16w+15; lane l: gate g=l&3, unit u=w*16+(l>>2).
// Replica ds_read_b128 gives lane l h-quad (l&15). Matvec: 16 groups, group n
// uses v_fmac_f32_dpp row_ror:n against PER-LANE PRE-ROTATED weight group n.
// Barrier = raw lgkmcnt(0)+s_barrier. x prefetched 2 steps deep (xA/xB).
#define DECLWR(n) \
    float Wr##n##0, Wr##n##1, Wr##n##2, Wr##n##3; \
    { int qs_ = (((l16 - (n)) & 15) << 2); \
      Wr##n##0 = vw[qs_]; Wr##n##1 = vw[qs_ + 1]; \
      Wr##n##2 = vw[qs_ + 2]; Wr##n##3 = vw[qs_ + 3]; }
#define FMACD(ACC, H, W, N) \
    asm("v_fmac_f32_dpp %0, %1, %2 row_ror:" #N " row_mask:0xf bank_mask:0xf" \
        : "+v"(ACC) : "v"(H), "v"(W));
#define RORF(n) { \
    FMACD(a0, hq.x, Wr##n##0, n) FMACD(a1, hq.y, Wr##n##1, n) \
    FMACD(a2, hq.z, Wr##n##2, n) FMACD(a3, hq.w, Wr##n##3, n) }

// one LSTM step; XR is used for this step then refilled with step S+2's x
#define SBODY(S, XR) { \
    int p_ = dir ? (len - 1 - (S)) : (S); \
    float xv = XR; \
    int pn_ = dir ? (len - 3 - (S)) : ((S) + 2); \
    pn_ = min(max(pn_, 0), T - 1); \
    XR = xg[(size_t)pn_ * NG]; \
    float4 hq = *(const float4*)(&hbuf[(S) & 1][l16 * 4]); \
    float a0 = xv, a1 = 0.f, a2 = 0.f, a3 = 0.f; \
    a0 = fmaf(hq.x, Wr00, a0); a1 = fmaf(hq.y, Wr01, a1); \
    a2 = fmaf(hq.z, Wr02, a2); a3 = fmaf(hq.w, Wr03, a3); \
    RORF(1)  RORF(2)  RORF(3)  RORF(4)  RORF(5) \
    RORF(6)  RORF(7)  RORF(8)  RORF(9)  RORF(10) \
    RORF(11) RORF(12) RORF(13) RORF(14) RORF(15) \
    float pre = (a0 + a1) + (a2 + a3); \
    bool isg = (g == 2); \
    float t_in = isg ? (2.f * pre) : (-pre); \
    float e_ = __expf(t_in); \
    float r_ = __builtin_amdgcn_rcpf(1.f + e_); \
    float val = isg ? fmaf(-2.f, r_, 1.f) : r_; \
    float vi = QBC(val, 0); \
    float vf = QBC(val, 1); \
    float vg = QBC(val, 2); \
    float vo = QBC(val, 3); \
    c = fmaf(vf, c, vi * vg); \
    float th = fmaf(-2.f, __builtin_amdgcn_rcpf(1.f + __expf(2.f * c)), 1.f); \
    float h = vo * th; \
    if (g == 0) { \
        hbuf[((S) & 1) ^ 1][u] = h; \
        outp[(size_t)p_ * DM + u] = h; \
    } \
    asm volatile("s_waitcnt lgkmcnt(0)\n\ts_barrier" ::: "memory"); }

__global__ __attribute__((amdgpu_flat_work_group_size(256, 256),
                          amdgpu_waves_per_eu(2, 2))) void k_scan(
    const float* __restrict__ xpB, const float* __restrict__ xpP,
    float* __restrict__ bodyM, float* __restrict__ punM,
    const int* __restrict__ lens,
    const float* __restrict__ bWhh_f, const float* __restrict__ bWhh_b,
    const float* __restrict__ pWhh_f, const float* __restrict__ pWhh_b) {
    int task = blockIdx.x, tid = threadIdx.x;
    int isPun = task >> 8;
    int sub = task & 255;
    int b = sub & 127, dir = sub >> 7;
    int T = isPun ? TPUN : TBODY;
    int len = lens[(isPun ? B : 0) + b];
    int w = tid >> 6, l = tid & 63;
    int g = l & 3, q = l >> 2;
    int u = w * 16 + q;
    int l16 = l & 15;
    const float* xp = (isPun ? xpP : xpB) + (size_t)b * T * NG + dir * G4;
    float* outp = (isPun ? punM : bodyM) + (size_t)b * T * DM + dir * HID;
    const float* Whh = isPun ? (dir ? pWhh_b : pWhh_f) : (dir ? bWhh_b : bWhh_f);

    // 64 weights (this lane's gate row) as named scalars, PRE-ROTATED so
    // group n matches row_ror:n of the replica hq. Volatile = load once.
    const volatile float* vw = Whh + (size_t)(g * 64 + u) * 64;
    DECLWR(0)  DECLWR(1)  DECLWR(2)  DECLWR(3)
    DECLWR(4)  DECLWR(5)  DECLWR(6)  DECLWR(7)
    DECLWR(8)  DECLWR(9)  DECLWR(10) DECLWR(11)
    DECLWR(12) DECLWR(13) DECLWR(14) DECLWR(15)

    __shared__ __align__(16) float hbuf[2][64];
    if (tid < 64) hbuf[0][tid] = 0.f;
    __syncthreads();

    if (len > 0) {
        const float* xg = xp + g * 64 + u;   // this lane's gate preact column
        float c = 0.f;
        // 2-deep x prefetch: xA for even steps, xB for odd steps
        int p0 = dir ? (len - 1) : 0;
        int p1 = dir ? (len - 2) : 1;
        p1 = min(max(p1, 0), T - 1);
        float xA = xg[(size_t)p0 * NG];
        float xB = xg[(size_t)p1 * NG];
        int s = 0;
        for (; s + 1 < len; s += 2) {
            SBODY(s, xA)
            SBODY(s + 1, xB)
        }
        if (s < len) { SBODY(s, xA) }
    }
    // tail zeroing: rows [len,T) must be 0 (replaces the global memset).
    // len ~= T for random data, so this is usually empty.
    if (g == 0) {
        for (int p = max(len, 0); p < T; ++p)
            outp[(size_t)p * DM + u] = 0.f;
    }
}

// ---------------- a_t = body_M.w1, b_p = pun_M.w2 (one wave per row) ----------------
__global__ __launch_bounds__(256) void k_rowdot(const float* __restrict__ bodyM,
                                                const float* __restrict__ punM,
                                                const float* __restrict__ w_u,
                                                float* __restrict__ a_body,
                                                float* __restrict__ a_pun) {
    int wid = (blockIdx.x * 256 + threadIdx.x) >> 6;
    int lane = threadIdx.x & 63;
    const int NB = B * TBODY;
    const float* src; const float* wv; float* dst;
    if (wid < NB) { src = bodyM + (size_t)wid * DM; wv = w_u; dst = a_body + wid; }
    else { src = punM + (size_t)(wid - NB) * DM; wv = w_u + DM; dst = a_pun + (wid - NB); }
    float2 v = ((const float2*)src)[lane];
    float2 w = ((const float2*)wv)[lane];
    float s = v.x * w.x + v.y * w.y;
    for (int o = 32; o; o >>= 1) s += __shfl_xor(s, o, 64);
    if (lane == 0) *dst = s;
}

// ---------------- align tile: m_t (full) + col partial maxes ----------------
// pk_fma inner product over dd-pairs (R17); pu stride 132, float4 I/O (R16).
__global__ __launch_bounds__(256) void k_align(
    const float* __restrict__ bodyM, const float* __restrict__ punM,
    const float* __restrict__ a_body, const float* __restrict__ a_pun,
    const float* __restrict__ w_u,
    float* __restrict__ m_t, float* __restrict__ colpart) {
    __shared__ float bw[64 * 132];
    __shared__ float pu[64 * 132];
    __shared__ float colred[64 * 16];
    int tid = threadIdx.x;
    int tt = blockIdx.x, b = blockIdx.y;
    int t0 = tt * 64;
    int ti = tid >> 4, pi = tid & 15;
    const float* w3 = w_u + 2 * DM;
    const float* bsrc = bodyM + ((size_t)b * TBODY + t0) * DM;
#pragma unroll
    for (int j = 0; j < 8; j++) {
        int e = tid + 256 * j;
        int i = e >> 5, c4 = e & 31;
        float4 v = *(const float4*)(bsrc + i * DM + c4 * 4);
        float4 wv = *(const float4*)(w3 + c4 * 4);
        v.x *= wv.x; v.y *= wv.y; v.z *= wv.z; v.w *= wv.w;
        *(float4*)(bw + i * 132 + c4 * 4) = v;
    }
    float aB[4];
#pragma unroll
    for (int a = 0; a < 4; a++) aB[a] = a_body[(size_t)b * TBODY + t0 + ti * 4 + a];
    float mrun[4] = {-1e30f, -1e30f, -1e30f, -1e30f};
    for (int pc = 0; pc < 4; pc++) {
        __syncthreads();
        const float* psrc = punM + ((size_t)b * TPUN + pc * 64) * DM;
#pragma unroll
        for (int j = 0; j < 8; j++) {
            int e = tid + 256 * j;
            int i = e >> 5, c4 = e & 31;
            float4 v = *(const float4*)(psrc + i * DM + c4 * 4);
            *(float4*)(pu + i * 132 + c4 * 4) = v;
        }
        __syncthreads();
        float aP[4];
#pragma unroll
        for (int c = 0; c < 4; c++) aP[c] = a_pun[(size_t)b * TPUN + pc * 64 + pi * 4 + c];
        f32x2 C2[4][4];
#pragma unroll
        for (int a = 0; a < 4; a++)
#pragma unroll
            for (int c = 0; c < 4; c++) C2[a][c] = (f32x2){0.f, 0.f};
        for (int d4 = 0; d4 < 32; d4++) {
            float4 bq[4];
#pragma unroll
            for (int a = 0; a < 4; a++) bq[a] = *(const float4*)(bw + (ti * 4 + a) * 132 + d4 * 4);
            float4 pq[4];
#pragma unroll
            for (int c = 0; c < 4; c++) pq[c] = *(const float4*)(pu + (pi * 4 + c) * 132 + d4 * 4);
#pragma unroll
            for (int a = 0; a < 4; a++) {
                f32x2 blo = {bq[a].x, bq[a].y};
                f32x2 bhi = {bq[a].z, bq[a].w};
#pragma unroll
                for (int c = 0; c < 4; c++) {
                    f32x2 plo = {pq[c].x, pq[c].y};
                    f32x2 phi = {pq[c].z, pq[c].w};
                    PKFMA2(C2[a][c], blo, plo)
                    PKFMA2(C2[a][c], bhi, phi)
                }
            }
        }
        float colv[4] = {-1e30f, -1e30f, -1e30f, -1e30f};
#pragma unroll
        for (int a = 0; a < 4; a++) {
            float rm = -1e30f;
#pragma unroll
            for (int c = 0; c < 4; c++) {
                float valv = (C2[a][c].x + C2[a][c].y) + aB[a] + aP[c];
                rm = fmaxf(rm, valv);
                colv[c] = fmaxf(colv[c], valv);
            }
#pragma unroll
            for (int o = 1; o < 16; o <<= 1) rm = fmaxf(rm, __shfl_xor(rm, o, 64));
            mrun[a] = fmaxf(mrun[a], rm);
        }
#pragma unroll
        for (int c = 0; c < 4; c++) colred[(pi * 4 + c) * 16 + ti] = colv[c];
        __syncthreads();
        if (tid < 64) {
            float m = -1e30f;
#pragma unroll
            for (int k = 0; k < 16; k++) m = fmaxf(m, colred[tid * 16 + k]);
            colpart[((size_t)b * 8 + tt) * TPUN + pc * 64 + tid] = m;
        }
    }
    if (pi == 0) {
#pragma unroll
        for (int a = 0; a < 4; a++) m_t[(size_t)b * TBODY + t0 + ti * 4 + a] = mrun[a];
    }
}

__global__ __launch_bounds__(256) void k_colmax(const float* __restrict__ colpart,
                                                float* __restrict__ m_p) {
    int b = blockIdx.x, p = threadIdx.x;
    float m = -1e30f;
    for (int tt = 0; tt < 8; tt++) m = fmaxf(m, colpart[((size_t)b * 8 + tt) * TPUN + p]);
    m_p[(size_t)b * TPUN + p] = m;
}

// ---------------- softmax + attention-weighted feature sums ----------------
__global__ __launch_bounds__(256) void k_feat(const float* __restrict__ bodyM,
                                              const float* __restrict__ punM,
                                              const float* __restrict__ m_t,
                                              const float* __restrict__ m_p,
                                              float* __restrict__ feat) {
    int bidx = blockIdx.x;
    int b = bidx & (B - 1), which = bidx >> 7;
    int n = which ? TPUN : TBODY;
    const float* sc = which ? (m_p + (size_t)b * TPUN) : (m_t + (size_t)b * TBODY);
    const float* src = which ? (punM + (size_t)b * TPUN * DM) : (bodyM + (size_t)b * TBODY * DM);
    float* dst = feat + (size_t)b * 256 + which * DM;
    int tid = threadIdx.x;
    __shared__ float e_lds[TBODY];
    __shared__ float red[8];
    __shared__ float red2[256];
    float mx = -1e30f;
    for (int t = tid; t < n; t += 256) mx = fmaxf(mx, sc[t]);
    for (int o = 32; o; o >>= 1) mx = fmaxf(mx, __shfl_xor(mx, o, 64));
    if ((tid & 63) == 0) red[tid >> 6] = mx;
    __syncthreads();
    mx = fmaxf(fmaxf(red[0], red[1]), fmaxf(red[2], red[3]));
    float se = 0.f;
    for (int t = tid; t < n; t += 256) {
        float ev = __expf(sc[t] - mx);
        e_lds[t] = ev;
        se += ev;
    }
    for (int o = 32; o; o >>= 1) se += __shfl_xor(se, o, 64);
    if ((tid & 63) == 0) red[4 + (tid >> 6)] = se;
    __syncthreads();
    se = red[4] + red[5] + red[6] + red[7];
    float inv = 1.f / se;
    int d = tid & 127, half = tid >> 7;
    float acc = 0.f;
    for (int t = half; t < n; t += 2) acc += e_lds[t] * src[(size_t)t * DM + d];
    red2[tid] = acc;
    __syncthreads();
    if (tid < DM) dst[tid] = (red2[tid] + red2[tid + 128]) * inv;
}

// ---------------- out = feat @ Wd^T + bd ----------------
__global__ __launch_bounds__(256) void k_out(const float* __restrict__ feat,
                                             const float* __restrict__ Wd,
                                             const float* __restrict__ bd,
                                             float* __restrict__ outp) {
    int b = blockIdx.x, tid = threadIdx.x;
    float v = feat[(size_t)b * 256 + tid];
    __shared__ float red[12];
#pragma unroll
    for (int pol = 0; pol < 3; pol++) {
        float s = v * Wd[pol * 256 + tid];
        for (int o = 32; o; o >>= 1) s += __shfl_xor(s, o, 64);
        if ((tid & 63) == 0) red[pol * 4 + (tid >> 6)] = s;
    }
    __syncthreads();
    if (tid < 3) outp[b * 3 + tid] = red[tid * 4] + red[tid * 4 + 1] + red[tid * 4 + 2] + red[tid * 4 + 3] + bd[tid];
}

extern "C" void kernel_launch(void* const* d_in, const int* in_sizes, int n_in,
                              void* d_out, int out_size, void* d_ws, size_t ws_size,
                              hipStream_t stream) {
    const int* body_idx = (const int*)d_in[0];
    const int* pun_idx  = (const int*)d_in[1];
    const float* emb    = (const float*)d_in[2];
    const float* w_u    = (const float*)d_in[3];
    const float* Wd     = (const float*)d_in[4];
    const float* bd     = (const float*)d_in[5];
    const float* bWih_f = (const float*)d_in[6];
    const float* bWhh_f = (const float*)d_in[7];
    const float* bb_f   = (const float*)d_in[8];
    const float* bWih_b = (const float*)d_in[9];
    const float* bWhh_b = (const float*)d_in[10];
    const float* bb_b   = (const float*)d_in[11];
    const float* pWih_f = (const float*)d_in[12];
    const float* pWhh_f = (const float*)d_in[13];
    const float* pb_f   = (const float*)d_in[14];
    const float* pWih_b = (const float*)d_in[15];
    const float* pWhh_b = (const float*)d_in[16];
    const float* pb_b   = (const float*)d_in[17];

    char* ws = (char*)d_ws;
    float* xpB   = (float*)(ws + OFF_XPB);
    float* xpP   = (float*)(ws + OFF_XPP);
    float* bodyM = (float*)(ws + OFF_BODYM);
    float* punM  = (float*)(ws + OFF_PUNM);
    u16* embb    = (u16*)(ws + OFF_EMBB);
    u16* Wcb     = (u16*)(ws + OFF_WCB);
    u16* Wcp     = (u16*)(ws + OFF_WCP);
    float* biasb = (float*)(ws + OFF_BIASB);
    float* biasp = (float*)(ws + OFF_BIASP);
    int* lens    = (int*)(ws + OFF_LENS);
    float* a_body = (float*)(ws + OFF_ABODY);
    float* a_pun  = (float*)(ws + OFF_APUN);
    float* m_t    = (float*)(ws + OFF_MT);
    float* m_p    = (float*)(ws + OFF_MP);
    float* colpart = (float*)(ws + OFF_COLP);
    float* feat   = (float*)(ws + OFF_FEAT);
    float* outp   = (float*)d_out;

    k_prep<<<dim3(17165), dim3(256), 0, stream>>>(
        emb, embb, body_idx, pun_idx, lens,
        bWih_f, bWih_b, bb_f, bb_b, pWih_f, pWih_b, pb_f, pb_b,
        Wcb, Wcp, biasb, biasp);
    k_gemm<<<dim3(512, 4), dim3(256), 0, stream>>>(body_idx, embb, Wcb, biasb, xpB);
    k_gemm<<<dim3(256, 4), dim3(256), 0, stream>>>(pun_idx, embb, Wcp, biasp, xpP);
    k_scan<<<dim3(512), dim3(256), 0, stream>>>(xpB, xpP, bodyM, punM, lens,
                                                bWhh_f, bWhh_b, pWhh_f, pWhh_b);
    k_rowdot<<<dim3(24576), dim3(256), 0, stream>>>(bodyM, punM, w_u, a_body, a_pun);
    k_align<<<dim3(8, 128), dim3(256), 0, stream>>>(bodyM, punM, a_body, a_pun, w_u, m_t, colpart);
    k_colmax<<<dim3(128), dim3(256), 0, stream>>>(colpart, m_p);
    k_feat<<<dim3(256), dim3(256), 0, stream>>>(bodyM, punM, m_t, m_p, feat);
    k_out<<<dim3(128), dim3(256), 0, stream>>>(feat, Wd, bd, outp);
}

// Round 16
// 587.752 us; speedup vs baseline: 1.2852x; 1.0098x over previous
//
#include <hip/hip_runtime.h>

// FGIAN BiLSTM+attention. R20: R19 (best: 593us) + two launch-level fusions,
// both math-free: (1) body+pun gemms merged into ONE launch (grid 768x4,
// decode from blockIdx.x) — removes a launch gap and lets pun tiles backfill
// CUs as body tiles drain; (2) k_colmax fused into k_feat (pun-side block
// computes m_p row-max from colpart inline; colpart is L2-resident) —
// deletes a dispatch + the m_p round-trip. k_scan FROZEN (R11 form, 233us).
// absmax must stay exactly 9.765625e-4.

#define B 128
#define TBODY 512
#define TPUN 256
#define EMB 300
#define EMBP 320
#define VOCAB 50000
#define HID 64
#define G4 256
#define NG 512
#define DM 128

typedef __attribute__((ext_vector_type(8))) short bf16x8;
typedef __attribute__((ext_vector_type(4))) float floatx4;
typedef __attribute__((ext_vector_type(2))) float f32x2;
typedef unsigned short u16;

// ---- workspace layout (bytes) ----
#define OFF_XPB   0u                    // f32 [B*TBODY*NG] = 134217728
#define OFF_XPP   134217728u            // f32 [B*TPUN*NG]  =  67108864
#define OFF_BODYM 201326592u            // f32 [B*TBODY*DM] =  33554432
#define OFF_PUNM  234881024u            // f32 [B*TPUN*DM]  =  16777216
#define OFF_SMALL 251658240u
// overlays in xpB (dead after k_scan):
#define OFF_ABODY (OFF_XPB + 0u)
#define OFF_APUN  (OFF_XPB + 262144u)
#define OFF_MT    (OFF_XPB + 393216u)
#define OFF_COLP  (OFF_XPB + 786432u)
// overlays in bodyM/punM (dead until k_scan fully overwrites them):
#define OFF_EMBB  OFF_BODYM             // bf16 [VOCAB*EMBP] = 32000000
#define OFF_WCB   OFF_PUNM
#define OFF_WCP   (OFF_PUNM + 327680u)
#define OFF_BIASB (OFF_PUNM + 655360u)
#define OFF_BIASP (OFF_PUNM + 657408u)
#define OFF_LENS  OFF_SMALL
#define OFF_FEAT  (OFF_SMALL + 1024u)

__device__ inline u16 f2bf(float v) {
    unsigned int u = __float_as_uint(v);
    unsigned int r = (u + 0x7FFFu + ((u >> 16) & 1u)) >> 16;  // RNE
    return (u16)r;
}

__device__ inline void gload_lds16(const void* g, void* l) {
    __builtin_amdgcn_global_load_lds(
        (const __attribute__((address_space(1))) unsigned int*)g,
        (__attribute__((address_space(3))) unsigned int*)l, 16, 0, 0);
}

// quad_perm broadcast of quad-lane gg (0..3): ctrl = gg*0x55 (HW-ok, R9-R11)
#define QBC(v, gg) __int_as_float(__builtin_amdgcn_update_dpp( \
    0, __float_as_int(v), (gg) * 0x55, 0xF, 0xF, true))
// packed dual f32 FMA (HW-ok, R6/R17)
#define PKFMA2(acc, a2, b2) \
    asm("v_pk_fma_f32 %0, %1, %2, %0" : "+v"(acc) : "v"(a2), "v"(b2));

// ---------------- fused prep: emb->bf16 | lens | weights concat ----------------
// blocks [0,15625): emb (4 elems/thread); [15625,15881): lens; rest: prep_w.
__global__ __launch_bounds__(256) void k_prep(
    const float* __restrict__ emb, u16* __restrict__ embb,
    const int* __restrict__ bidx, const int* __restrict__ pidx,
    int* __restrict__ lens,
    const float* __restrict__ bWih_f, const float* __restrict__ bWih_b,
    const float* __restrict__ bb_f, const float* __restrict__ bb_b,
    const float* __restrict__ pWih_f, const float* __restrict__ pWih_b,
    const float* __restrict__ pb_f, const float* __restrict__ pb_b,
    u16* __restrict__ Wcb, u16* __restrict__ Wcp,
    float* __restrict__ biasb, float* __restrict__ biasp) {
    int blk = blockIdx.x, tid = threadIdx.x;
    if (blk < 15625) {
        int e4 = (blk * 256 + tid) * 4;  // exactly VOCAB*EMBP/4 threads
        int row = e4 / EMBP, d = e4 - row * EMBP;
        u16 o0 = 0, o1 = 0, o2 = 0, o3 = 0;
        if (d < EMB) {
            float4 v = *(const float4*)(emb + (size_t)row * EMB + d);
            o0 = f2bf(v.x); o1 = f2bf(v.y); o2 = f2bf(v.z); o3 = f2bf(v.w);
        }
        ushort4 o = {o0, o1, o2, o3};
        *(ushort4*)(embb + e4) = o;
    } else if (blk < 15625 + 256) {
        int j = blk - 15625;
        const int* src; int n;
        if (j < B) { src = bidx + (size_t)j * TBODY; n = TBODY; }
        else       { src = pidx + (size_t)(j - B) * TPUN; n = TPUN; }
        int c = 0;
        for (int t = tid; t < n; t += 256) c += (src[t] != 0) ? 1 : 0;
        for (int o = 32; o; o >>= 1) c += __shfl_xor(c, o, 64);
        __shared__ int red[4];
        if ((tid & 63) == 0) red[tid >> 6] = c;
        __syncthreads();
        if (tid == 0) lens[j] = red[0] + red[1] + red[2] + red[3];
    } else {
        int e = (blk - 15881) * 256 + tid;   // 1284 blocks cover 328704 exactly
        const int WSZ = NG * EMBP;  // 163840
        if (e < WSZ) {
            int g = e / EMBP, d = e - g * EMBP;
            float v = 0.f;
            if (d < EMB) v = (g < G4) ? bWih_f[g * EMB + d] : bWih_b[(g - G4) * EMB + d];
            Wcb[e] = f2bf(v);
        } else if (e < 2 * WSZ) {
            int ee = e - WSZ;
            int g = ee / EMBP, d = ee - g * EMBP;
            float v = 0.f;
            if (d < EMB) v = (g < G4) ? pWih_f[g * EMB + d] : pWih_b[(g - G4) * EMB + d];
            Wcp[ee] = f2bf(v);
        } else if (e < 2 * WSZ + NG) {
            int g = e - 2 * WSZ;
            biasb[g] = (g < G4) ? bb_f[g] : bb_b[g - G4];
        } else if (e < 2 * WSZ + 2 * NG) {
            int g = e - 2 * WSZ - NG;
            biasp[g] = (g < G4) ? pb_f[g] : pb_b[g - G4];
        }
    }
}

// ---------------- 128x128 bf16 MFMA GEMM, MERGED body+pun launch ------------
// blockIdx.x < 512: body tile; else pun tile (x-512). Same tile code.
__global__ __launch_bounds__(256) void k_gemm(
    const int* __restrict__ bidx, const int* __restrict__ pidx,
    const u16* __restrict__ embb,
    const u16* __restrict__ Wcb, const u16* __restrict__ Wcp,
    const float* __restrict__ biasb, const float* __restrict__ biasp,
    float* __restrict__ xpB, float* __restrict__ xpP) {
    __shared__ u16 As[128 * 32];
    __shared__ u16 Bs[128 * 32];
    int tid = threadIdx.x, wave = tid >> 6, lane = tid & 63;
    int bx = blockIdx.x;
    bool isP = (bx >= 512);
    int xblk = isP ? (bx - 512) : bx;
    const int* idx = isP ? pidx : bidx;
    const u16* Wc = isP ? Wcp : Wcb;
    const float* biasc = isP ? biasp : biasb;
    float* out = isP ? xpP : xpB;
    int m0 = xblk * 128, g0 = blockIdx.y * 128;

    const u16* agp[2]; const u16* bgp[2];
    u16* asd[2]; u16* bsd[2];
#pragma unroll
    for (int j = 0; j < 2; j++) {
        int rbase = wave * 32 + j * 16;
        int r = rbase + (lane >> 2);
        int clog = (lane & 3) ^ (r & 3);
        int arow = idx[m0 + r];
        agp[j] = embb + (size_t)arow * EMBP + clog * 8;
        bgp[j] = Wc + (size_t)(g0 + r) * EMBP + clog * 8;
        asd[j] = As + rbase * 32;
        bsd[j] = Bs + rbase * 32;
    }

    int l15 = lane & 15, quad = lane >> 4;
    int mt0 = (wave >> 1) * 4, nt0 = (wave & 1) * 4;
    const u16* ard[4]; const u16* brd[4];
#pragma unroll
    for (int a = 0; a < 4; a++) {
        int r = (mt0 + a) * 16 + l15;
        ard[a] = As + r * 32 + ((quad ^ (r & 3)) * 8);
        int n = (nt0 + a) * 16 + l15;
        brd[a] = Bs + n * 32 + ((quad ^ (n & 3)) * 8);
    }

    floatx4 acc[4][4];
#pragma unroll
    for (int a = 0; a < 4; a++)
#pragma unroll
        for (int c = 0; c < 4; c++) acc[a][c] = (floatx4){0.f, 0.f, 0.f, 0.f};

    for (int k0 = 0; k0 < EMBP; k0 += 32) {
#pragma unroll
        for (int j = 0; j < 2; j++) {
            gload_lds16(agp[j] + k0, asd[j]);
            gload_lds16(bgp[j] + k0, bsd[j]);
        }
        __syncthreads();
        bf16x8 af[4], bfr[4];
#pragma unroll
        for (int a = 0; a < 4; a++) { af[a] = *(const bf16x8*)ard[a]; bfr[a] = *(const bf16x8*)brd[a]; }
#pragma unroll
        for (int a = 0; a < 4; a++)
#pragma unroll
            for (int c = 0; c < 4; c++)
                acc[a][c] = __builtin_amdgcn_mfma_f32_16x16x32_bf16(af[a], bfr[c], acc[a][c], 0, 0, 0);
        __syncthreads();
    }

#pragma unroll
    for (int c = 0; c < 4; c++) {
        int gcol = g0 + (nt0 + c) * 16 + l15;
        float bv = biasc[gcol];
#pragma unroll
        for (int a = 0; a < 4; a++) {
            int row0 = m0 + (mt0 + a) * 16 + quad * 4;
#pragma unroll
            for (int rg = 0; rg < 4; rg++)
                out[(size_t)(row0 + rg) * NG + gcol] = acc[a][c][rg] + bv;
        }
    }
}

// ---------------- LSTM scans: 1 block (4 waves) per (seq,dir,b) ----------------
// wave w owns units 16w..16w+15; lane l: gate g=l&3, unit u=w*16+(l>>2).
// Replica ds_read_b128 gives lane l h-quad (l&15). Matvec: 16 groups, group n
// uses v_fmac_f32_dpp row_ror:n against PER-LANE PRE-ROTATED weight group n.
// Barrier = raw lgkmcnt(0)+s_barrier. x prefetched 2 steps deep (xA/xB).
#define DECLWR(n) \
    float Wr##n##0, Wr##n##1, Wr##n##2, Wr##n##3; \
    { int qs_ = (((l16 - (n)) & 15) << 2); \
      Wr##n##0 = vw[qs_]; Wr##n##1 = vw[qs_ + 1]; \
      Wr##n##2 = vw[qs_ + 2]; Wr##n##3 = vw[qs_ + 3]; }
#define FMACD(ACC, H, W, N) \
    asm("v_fmac_f32_dpp %0, %1, %2 row_ror:" #N " row_mask:0xf bank_mask:0xf" \
        : "+v"(ACC) : "v"(H), "v"(W));
#define RORF(n) { \
    FMACD(a0, hq.x, Wr##n##0, n) FMACD(a1, hq.y, Wr##n##1, n) \
    FMACD(a2, hq.z, Wr##n##2, n) FMACD(a3, hq.w, Wr##n##3, n) }

// one LSTM step; XR is used for this step then refilled with step S+2's x
#define SBODY(S, XR) { \
    int p_ = dir ? (len - 1 - (S)) : (S); \
    float xv = XR; \
    int pn_ = dir ? (len - 3 - (S)) : ((S) + 2); \
    pn_ = min(max(pn_, 0), T - 1); \
    XR = xg[(size_t)pn_ * NG]; \
    float4 hq = *(const float4*)(&hbuf[(S) & 1][l16 * 4]); \
    float a0 = xv, a1 = 0.f, a2 = 0.f, a3 = 0.f; \
    a0 = fmaf(hq.x, Wr00, a0); a1 = fmaf(hq.y, Wr01, a1); \
    a2 = fmaf(hq.z, Wr02, a2); a3 = fmaf(hq.w, Wr03, a3); \
    RORF(1)  RORF(2)  RORF(3)  RORF(4)  RORF(5) \
    RORF(6)  RORF(7)  RORF(8)  RORF(9)  RORF(10) \
    RORF(11) RORF(12) RORF(13) RORF(14) RORF(15) \
    float pre = (a0 + a1) + (a2 + a3); \
    bool isg = (g == 2); \
    float t_in = isg ? (2.f * pre) : (-pre); \
    float e_ = __expf(t_in); \
    float r_ = __builtin_amdgcn_rcpf(1.f + e_); \
    float val = isg ? fmaf(-2.f, r_, 1.f) : r_; \
    float vi = QBC(val, 0); \
    float vf = QBC(val, 1); \
    float vg = QBC(val, 2); \
    float vo = QBC(val, 3); \
    c = fmaf(vf, c, vi * vg); \
    float th = fmaf(-2.f, __builtin_amdgcn_rcpf(1.f + __expf(2.f * c)), 1.f); \
    float h = vo * th; \
    if (g == 0) { \
        hbuf[((S) & 1) ^ 1][u] = h; \
        outp[(size_t)p_ * DM + u] = h; \
    } \
    asm volatile("s_waitcnt lgkmcnt(0)\n\ts_barrier" ::: "memory"); }

__global__ __attribute__((amdgpu_flat_work_group_size(256, 256),
                          amdgpu_waves_per_eu(2, 2))) void k_scan(
    const float* __restrict__ xpB, const float* __restrict__ xpP,
    float* __restrict__ bodyM, float* __restrict__ punM,
    const int* __restrict__ lens,
    const float* __restrict__ bWhh_f, const float* __restrict__ bWhh_b,
    const float* __restrict__ pWhh_f, const float* __restrict__ pWhh_b) {
    int task = blockIdx.x, tid = threadIdx.x;
    int isPun = task >> 8;
    int sub = task & 255;
    int b = sub & 127, dir = sub >> 7;
    int T = isPun ? TPUN : TBODY;
    int len = lens[(isPun ? B : 0) + b];
    int w = tid >> 6, l = tid & 63;
    int g = l & 3, q = l >> 2;
    int u = w * 16 + q;
    int l16 = l & 15;
    const float* xp = (isPun ? xpP : xpB) + (size_t)b * T * NG + dir * G4;
    float* outp = (isPun ? punM : bodyM) + (size_t)b * T * DM + dir * HID;
    const float* Whh = isPun ? (dir ? pWhh_b : pWhh_f) : (dir ? bWhh_b : bWhh_f);

    // 64 weights (this lane's gate row) as named scalars, PRE-ROTATED so
    // group n matches row_ror:n of the replica hq. Volatile = load once.
    const volatile float* vw = Whh + (size_t)(g * 64 + u) * 64;
    DECLWR(0)  DECLWR(1)  DECLWR(2)  DECLWR(3)
    DECLWR(4)  DECLWR(5)  DECLWR(6)  DECLWR(7)
    DECLWR(8)  DECLWR(9)  DECLWR(10) DECLWR(11)
    DECLWR(12) DECLWR(13) DECLWR(14) DECLWR(15)

    __shared__ __align__(16) float hbuf[2][64];
    if (tid < 64) hbuf[0][tid] = 0.f;
    __syncthreads();

    if (len > 0) {
        const float* xg = xp + g * 64 + u;   // this lane's gate preact column
        float c = 0.f;
        // 2-deep x prefetch: xA for even steps, xB for odd steps
        int p0 = dir ? (len - 1) : 0;
        int p1 = dir ? (len - 2) : 1;
        p1 = min(max(p1, 0), T - 1);
        float xA = xg[(size_t)p0 * NG];
        float xB = xg[(size_t)p1 * NG];
        int s = 0;
        for (; s + 1 < len; s += 2) {
            SBODY(s, xA)
            SBODY(s + 1, xB)
        }
        if (s < len) { SBODY(s, xA) }
    }
    // tail zeroing: rows [len,T) must be 0 (replaces the global memset).
    // len ~= T for random data, so this is usually empty.
    if (g == 0) {
        for (int p = max(len, 0); p < T; ++p)
            outp[(size_t)p * DM + u] = 0.f;
    }
}

// ---------------- a_t = body_M.w1, b_p = pun_M.w2 (one wave per row) ----------------
__global__ __launch_bounds__(256) void k_rowdot(const float* __restrict__ bodyM,
                                                const float* __restrict__ punM,
                                                const float* __restrict__ w_u,
                                                float* __restrict__ a_body,
                                                float* __restrict__ a_pun) {
    int wid = (blockIdx.x * 256 + threadIdx.x) >> 6;
    int lane = threadIdx.x & 63;
    const int NB = B * TBODY;
    const float* src; const float* wv; float* dst;
    if (wid < NB) { src = bodyM + (size_t)wid * DM; wv = w_u; dst = a_body + wid; }
    else { src = punM + (size_t)(wid - NB) * DM; wv = w_u + DM; dst = a_pun + (wid - NB); }
    float2 v = ((const float2*)src)[lane];
    float2 w = ((const float2*)wv)[lane];
    float s = v.x * w.x + v.y * w.y;
    for (int o = 32; o; o >>= 1) s += __shfl_xor(s, o, 64);
    if (lane == 0) *dst = s;
}

// ---------------- align tile: m_t (full) + col partial maxes ----------------
// pk_fma inner product over dd-pairs (R17); pu stride 132, float4 I/O (R16).
__global__ __launch_bounds__(256) void k_align(
    const float* __restrict__ bodyM, const float* __restrict__ punM,
    const float* __restrict__ a_body, const float* __restrict__ a_pun,
    const float* __restrict__ w_u,
    float* __restrict__ m_t, float* __restrict__ colpart) {
    __shared__ float bw[64 * 132];
    __shared__ float pu[64 * 132];
    __shared__ float colred[64 * 16];
    int tid = threadIdx.x;
    int tt = blockIdx.x, b = blockIdx.y;
    int t0 = tt * 64;
    int ti = tid >> 4, pi = tid & 15;
    const float* w3 = w_u + 2 * DM;
    const float* bsrc = bodyM + ((size_t)b * TBODY + t0) * DM;
#pragma unroll
    for (int j = 0; j < 8; j++) {
        int e = tid + 256 * j;
        int i = e >> 5, c4 = e & 31;
        float4 v = *(const float4*)(bsrc + i * DM + c4 * 4);
        float4 wv = *(const float4*)(w3 + c4 * 4);
        v.x *= wv.x; v.y *= wv.y; v.z *= wv.z; v.w *= wv.w;
        *(float4*)(bw + i * 132 + c4 * 4) = v;
    }
    float aB[4];
#pragma unroll
    for (int a = 0; a < 4; a++) aB[a] = a_body[(size_t)b * TBODY + t0 + ti * 4 + a];
    float mrun[4] = {-1e30f, -1e30f, -1e30f, -1e30f};
    for (int pc = 0; pc < 4; pc++) {
        __syncthreads();
        const float* psrc = punM + ((size_t)b * TPUN + pc * 64) * DM;
#pragma unroll
        for (int j = 0; j < 8; j++) {
            int e = tid + 256 * j;
            int i = e >> 5, c4 = e & 31;
            float4 v = *(const float4*)(psrc + i * DM + c4 * 4);
            *(float4*)(pu + i * 132 + c4 * 4) = v;
        }
        __syncthreads();
        float aP[4];
#pragma unroll
        for (int c = 0; c < 4; c++) aP[c] = a_pun[(size_t)b * TPUN + pc * 64 + pi * 4 + c];
        f32x2 C2[4][4];
#pragma unroll
        for (int a = 0; a < 4; a++)
#pragma unroll
            for (int c = 0; c < 4; c++) C2[a][c] = (f32x2){0.f, 0.f};
        for (int d4 = 0; d4 < 32; d4++) {
            float4 bq[4];
#pragma unroll
            for (int a = 0; a < 4; a++) bq[a] = *(const float4*)(bw + (ti * 4 + a) * 132 + d4 * 4);
            float4 pq[4];
#pragma unroll
            for (int c = 0; c < 4; c++) pq[c] = *(const float4*)(pu + (pi * 4 + c) * 132 + d4 * 4);
#pragma unroll
            for (int a = 0; a < 4; a++) {
                f32x2 blo = {bq[a].x, bq[a].y};
                f32x2 bhi = {bq[a].z, bq[a].w};
#pragma unroll
                for (int c = 0; c < 4; c++) {
                    f32x2 plo = {pq[c].x, pq[c].y};
                    f32x2 phi = {pq[c].z, pq[c].w};
                    PKFMA2(C2[a][c], blo, plo)
                    PKFMA2(C2[a][c], bhi, phi)
                }
            }
        }
        float colv[4] = {-1e30f, -1e30f, -1e30f, -1e30f};
#pragma unroll
        for (int a = 0; a < 4; a++) {
            float rm = -1e30f;
#pragma unroll
            for (int c = 0; c < 4; c++) {
                float valv = (C2[a][c].x + C2[a][c].y) + aB[a] + aP[c];
                rm = fmaxf(rm, valv);
                colv[c] = fmaxf(colv[c], valv);
            }
#pragma unroll
            for (int o = 1; o < 16; o <<= 1) rm = fmaxf(rm, __shfl_xor(rm, o, 64));
            mrun[a] = fmaxf(mrun[a], rm);
        }
#pragma unroll
        for (int c = 0; c < 4; c++) colred[(pi * 4 + c) * 16 + ti] = colv[c];
        __syncthreads();
        if (tid < 64) {
            float m = -1e30f;
#pragma unroll
            for (int k = 0; k < 16; k++) m = fmaxf(m, colred[tid * 16 + k]);
            colpart[((size_t)b * 8 + tt) * TPUN + pc * 64 + tid] = m;
        }
    }
    if (pi == 0) {
#pragma unroll
        for (int a = 0; a < 4; a++) m_t[(size_t)b * TBODY + t0 + ti * 4 + a] = mrun[a];
    }
}

// ---------------- softmax + attention-weighted feature sums ----------------
// R20: pun-side blocks compute m_p inline from colpart (k_colmax fused away).
__global__ __launch_bounds__(256) void k_feat(const float* __restrict__ bodyM,
                                              const float* __restrict__ punM,
                                              const float* __restrict__ m_t,
                                              const float* __restrict__ colpart,
                                              float* __restrict__ feat) {
    int bidx = blockIdx.x;
    int b = bidx & (B - 1), which = bidx >> 7;
    int n = which ? TPUN : TBODY;
    const float* src = which ? (punM + (size_t)b * TPUN * DM) : (bodyM + (size_t)b * TBODY * DM);
    float* dst = feat + (size_t)b * 256 + which * DM;
    int tid = threadIdx.x;
    __shared__ float e_lds[TBODY];
    __shared__ float red[8];
    __shared__ float red2[256];
    float mx = -1e30f;
    for (int t = tid; t < n; t += 256) {
        float v;
        if (which) {
            v = -1e30f;
#pragma unroll
            for (int tt = 0; tt < 8; tt++)
                v = fmaxf(v, colpart[((size_t)b * 8 + tt) * TPUN + t]);
        } else {
            v = m_t[(size_t)b * TBODY + t];
        }
        e_lds[t] = v;
        mx = fmaxf(mx, v);
    }
    for (int o = 32; o; o >>= 1) mx = fmaxf(mx, __shfl_xor(mx, o, 64));
    if ((tid & 63) == 0) red[tid >> 6] = mx;
    __syncthreads();
    mx = fmaxf(fmaxf(red[0], red[1]), fmaxf(red[2], red[3]));
    float se = 0.f;
    for (int t = tid; t < n; t += 256) {
        float ev = __expf(e_lds[t] - mx);
        e_lds[t] = ev;
        se += ev;
    }
    for (int o = 32; o; o >>= 1) se += __shfl_xor(se, o, 64);
    if ((tid & 63) == 0) red[4 + (tid >> 6)] = se;
    __syncthreads();
    se = red[4] + red[5] + red[6] + red[7];
    float inv = 1.f / se;
    int d = tid & 127, half = tid >> 7;
    float acc = 0.f;
    for (int t = half; t < n; t += 2) acc += e_lds[t] * src[(size_t)t * DM + d];
    red2[tid] = acc;
    __syncthreads();
    if (tid < DM) dst[tid] = (red2[tid] + red2[tid + 128]) * inv;
}

// ---------------- out = feat @ Wd^T + bd ----------------
__global__ __launch_bounds__(256) void k_out(const float* __restrict__ feat,
                                             const float* __restrict__ Wd,
                                             const float* __restrict__ bd,
                                             float* __restrict__ outp) {
    int b = blockIdx.x, tid = threadIdx.x;
    float v = feat[(size_t)b * 256 + tid];
    __shared__ float red[12];
#pragma unroll
    for (int pol = 0; pol < 3; pol++) {
        float s = v * Wd[pol * 256 + tid];
        for (int o = 32; o; o >>= 1) s += __shfl_xor(s, o, 64);
        if ((tid & 63) == 0) red[pol * 4 + (tid >> 6)] = s;
    }
    __syncthreads();
    if (tid < 3) outp[b * 3 + tid] = red[tid * 4] + red[tid * 4 + 1] + red[tid * 4 + 2] + red[tid * 4 + 3] + bd[tid];
}

extern "C" void kernel_launch(void* const* d_in, const int* in_sizes, int n_in,
                              void* d_out, int out_size, void* d_ws, size_t ws_size,
                              hipStream_t stream) {
    const int* body_idx = (const int*)d_in[0];
    const int* pun_idx  = (const int*)d_in[1];
    const float* emb    = (const float*)d_in[2];
    const float* w_u    = (const float*)d_in[3];
    const float* Wd     = (const float*)d_in[4];
    const float* bd     = (const float*)d_in[5];
    const float* bWih_f = (const float*)d_in[6];
    const float* bWhh_f = (const float*)d_in[7];
    const float* bb_f   = (const float*)d_in[8];
    const float* bWih_b = (const float*)d_in[9];
    const float* bWhh_b = (const float*)d_in[10];
    const float* bb_b   = (const float*)d_in[11];
    const float* pWih_f = (const float*)d_in[12];
    const float* pWhh_f = (const float*)d_in[13];
    const float* pb_f   = (const float*)d_in[14];
    const float* pWih_b = (const float*)d_in[15];
    const float* pWhh_b = (const float*)d_in[16];
    const float* pb_b   = (const float*)d_in[17];

    char* ws = (char*)d_ws;
    float* xpB   = (float*)(ws + OFF_XPB);
    float* xpP   = (float*)(ws + OFF_XPP);
    float* bodyM = (float*)(ws + OFF_BODYM);
    float* punM  = (float*)(ws + OFF_PUNM);
    u16* embb    = (u16*)(ws + OFF_EMBB);
    u16* Wcb     = (u16*)(ws + OFF_WCB);
    u16* Wcp     = (u16*)(ws + OFF_WCP);
    float* biasb = (float*)(ws + OFF_BIASB);
    float* biasp = (float*)(ws + OFF_BIASP);
    int* lens    = (int*)(ws + OFF_LENS);
    float* a_body = (float*)(ws + OFF_ABODY);
    float* a_pun  = (float*)(ws + OFF_APUN);
    float* m_t    = (float*)(ws + OFF_MT);
    float* colpart = (float*)(ws + OFF_COLP);
    float* feat   = (float*)(ws + OFF_FEAT);
    float* outp   = (float*)d_out;

    k_prep<<<dim3(17165), dim3(256), 0, stream>>>(
        emb, embb, body_idx, pun_idx, lens,
        bWih_f, bWih_b, bb_f, bb_b, pWih_f, pWih_b, pb_f, pb_b,
        Wcb, Wcp, biasb, biasp);
    k_gemm<<<dim3(768, 4), dim3(256), 0, stream>>>(body_idx, pun_idx, embb,
                                                   Wcb, Wcp, biasb, biasp,
                                                   xpB, xpP);
    k_scan<<<dim3(512), dim3(256), 0, stream>>>(xpB, xpP, bodyM, punM, lens,
                                                bWhh_f, bWhh_b, pWhh_f, pWhh_b);
    k_rowdot<<<dim3(24576), dim3(256), 0, stream>>>(bodyM, punM, w_u, a_body, a_pun);
    k_align<<<dim3(8, 128), dim3(256), 0, stream>>>(bodyM, punM, a_body, a_pun, w_u, m_t, colpart);
    k_feat<<<dim3(256), dim3(256), 0, stream>>>(bodyM, punM, m_t, colpart, feat);
    k_out<<<dim3(128), dim3(256), 0, stream>>>(feat, Wd, bd, outp);
}